// Round 5
// baseline (262.171 us; speedup 1.0000x reference)
//
#include <hip/hip_runtime.h>
#include <hip/hip_bf16.h>

// z = x[B,D] . W[O,D]^T + bias[O]; out = z*z.  B=131072, D=128, O=256. fp32 I/O.
// R5: fix the x load path. Previous versions gathered 16B from 16 rows per
// load instr (16 line-requests/instr, ~2x redundant) -> address/MSHR bound at
// ~2 TB/s. Now: fully-coalesced float4 loads (2 whole rows per wave-instr),
// in-reg fp32->bf16 pack, per-wave double-buffered LDS x-tile (pitch 136 bf16),
// b128 A-frag reads. Same-wave DS is in-order => NO __syncthreads anywhere.
// W register-resident per wave; LDS-transpose epilogue reuses the x buffer.

#define B_ROWS 131072
#define D_DIM  128
#define O_DIM  256
#define THREADS 256
#define NBLOCKS 2048
#define TILES 4
#define ROWS_PER_BLOCK (TILES * 16)   // 64
#define XT_PITCH 136                  // bf16 elems: 128 + 8 pad; row = 272 B (16B-aligned)

using bf16x8 = __attribute__((ext_vector_type(8))) short;  // 8 bf16 (4 VGPRs)
using f32x4  = __attribute__((ext_vector_type(4))) float;

__device__ __forceinline__ short bf16rne(float f) {
    unsigned u = __builtin_bit_cast(unsigned, f);
    u += 0x7FFFu + ((u >> 16) & 1u);        // round-to-nearest-even (finite inputs)
    return (short)(u >> 16);
}

__device__ __forceinline__ short4 pack4(float4 v) {
    short4 p;
    p.x = bf16rne(v.x); p.y = bf16rne(v.y);
    p.z = bf16rne(v.z); p.w = bf16rne(v.w);
    return p;
}

__device__ __forceinline__ bf16x8 pack8(float4 h0, float4 h1) {
    bf16x8 t;
    t[0] = bf16rne(h0.x); t[1] = bf16rne(h0.y);
    t[2] = bf16rne(h0.z); t[3] = bf16rne(h0.w);
    t[4] = bf16rne(h1.x); t[5] = bf16rne(h1.y);
    t[6] = bf16rne(h1.z); t[7] = bf16rne(h1.w);
    return t;
}

__global__ __launch_bounds__(THREADS, 3)
void hyper_linear_sq_kernel(const float* __restrict__ x,
                            const float* __restrict__ weight,
                            const float* __restrict__ bias,
                            float* __restrict__ out) {
    // 2 bufs x 4 waves x (16 rows x 136 bf16) = 34816 B
    __shared__ short xt[2][4][16 * XT_PITCH];

    const int lane  = threadIdx.x & 63;
    const int wid   = threadIdx.x >> 6;    // column quarter
    const int n16   = lane & 15;
    const int quad  = lane >> 4;
    const int cbase = wid * 64;
    const int half  = lane >> 5;           // row parity within a 2-row load
    const int l32   = lane & 31;           // col group for coalesced loads

    // ---- Persistent B fragments: bfrag[ct][ks][j] = W[cbase+ct*16+n16][ks*32+quad*8+j]
    bf16x8 bfrag[4][4];
    #pragma unroll
    for (int ct = 0; ct < 4; ++ct) {
        const float* wr = weight + (cbase + ct * 16 + n16) * D_DIM + quad * 8;
        #pragma unroll
        for (int ks = 0; ks < 4; ++ks) {
            float4 h0 = *(const float4*)(wr + ks * 32);
            float4 h1 = *(const float4*)(wr + ks * 32 + 4);
            bfrag[ct][ks] = pack8(h0, h1);
        }
    }

    float bv[4];
    #pragma unroll
    for (int ct = 0; ct < 4; ++ct) bv[ct] = bias[cbase + ct * 16 + n16];

    const long rowbase0 = (long)blockIdx.x * ROWS_PER_BLOCK;
    // coalesced: load i covers rows (tilebase + 2i + half), cols l32*4..+3
    const float* xld = x + (rowbase0 + half) * D_DIM + l32 * 4;

    // ---- Prologue: tile 0 -> buf 0
    {
        float4 r0[8];
        #pragma unroll
        for (int i = 0; i < 8; ++i)
            r0[i] = *(const float4*)(xld + (long)(2 * i) * D_DIM);
        #pragma unroll
        for (int i = 0; i < 8; ++i)
            *(short4*)&xt[0][wid][(2 * i + half) * XT_PITCH + l32 * 4] = pack4(r0[i]);
    }

    #pragma unroll
    for (int t = 0; t < TILES; ++t) {
        const int buf = t & 1;

        // prefetch next tile's rows (coalesced, dense lines)
        float4 rn[8];
        if (t + 1 < TILES) {
            const float* xn = xld + (long)(t + 1) * 16 * D_DIM;
            #pragma unroll
            for (int i = 0; i < 8; ++i)
                rn[i] = *(const float4*)(xn + (long)(2 * i) * D_DIM);
        }

        // A fragments from LDS (b128; bank-phase uniform at pitch 136)
        bf16x8 a[4];
        #pragma unroll
        for (int ks = 0; ks < 4; ++ks)
            a[ks] = *(const bf16x8*)&xt[buf][wid][n16 * XT_PITCH + ks * 32 + quad * 8];

        f32x4 acc[4];
        #pragma unroll
        for (int ct = 0; ct < 4; ++ct) acc[ct] = (f32x4){0.f, 0.f, 0.f, 0.f};

        #pragma unroll
        for (int ks = 0; ks < 4; ++ks) {
            #pragma unroll
            for (int ct = 0; ct < 4; ++ct) {
                acc[ct] = __builtin_amdgcn_mfma_f32_16x16x32_bf16(a[ks], bfrag[ct][ks], acc[ct], 0, 0, 0);
            }
        }

        // stage prefetched tile into the other buffer (same-wave DS is in-order,
        // so next iteration's a-frag reads see these writes; no barrier needed)
        if (t + 1 < TILES) {
            #pragma unroll
            for (int i = 0; i < 8; ++i)
                *(short4*)&xt[buf ^ 1][wid][(2 * i + half) * XT_PITCH + l32 * 4] = pack4(rn[i]);
        }

        // ---- epilogue: reuse current buffer as f32 [16][68] transpose tile
        float* ft = (float*)&xt[buf][wid][0];   // pitch 68 f32 (= 272 B)
        #pragma unroll
        for (int ct = 0; ct < 4; ++ct) {
            #pragma unroll
            for (int r = 0; r < 4; ++r) {
                float z = acc[ct][r] + bv[ct];
                ft[(quad * 4 + r) * 68 + ct * 16 + n16] = z * z;
            }
        }
        #pragma unroll
        for (int s = 0; s < 4; ++s) {
            f32x4 v = *(const f32x4*)&ft[(s * 4 + quad) * 68 + n16 * 4];
            long row = rowbase0 + t * 16 + s * 4 + quad;
            __builtin_nontemporal_store(v, (f32x4*)(out + row * O_DIM + cbase + n16 * 4));
        }
    }
}

extern "C" void kernel_launch(void* const* d_in, const int* in_sizes, int n_in,
                              void* d_out, int out_size, void* d_ws, size_t ws_size,
                              hipStream_t stream) {
    const float* x    = (const float*)d_in[0];
    const float* w    = (const float*)d_in[1];
    const float* bias = (const float*)d_in[2];
    float* out        = (float*)d_out;
    hipLaunchKernelGGL(hyper_linear_sq_kernel, dim3(NBLOCKS), dim3(THREADS), 0, stream,
                       x, w, bias, out);
}